// Round 8
// baseline (247.940 us; speedup 1.0000x reference)
//
#include <hip/hip_runtime.h>
#include <hip/hip_bf16.h>

// ---------------------------------------------------------------------------
// CausalMultiHeadedSelfAttention on gfx950.
// R16: ONE change vs R15 -- attn fused dual-q-tile step (attn_step2) for
// kt<=q0t: each kf/vf ds_read_b128 feeds BOTH q-tiles' MFMAs (halves the
// K/V fragment reads), ONE lgkmcnt serial-chain drain per iteration instead
// of two, pack inside the mt-loop (2 f32x4 scores live vs 4).  This is
// R14's attn idea measured SOLO: R14 bundled it with a gemm_dev signature
// change (rule-#19 perturbation, qkv 70.7->85.3us) and split-K atomics
// (~16.8M fp32 atomicAdds), so its isolated effect was never observed; it
// was numerically correct there (absmax unchanged).
// gemm_dev body/signature/instantiations BYTE-IDENTICAL to R15 (qkv frozen:
// 70.2us, MfmaUtil 29, FETCH 58.5MB).  Ps -> [4][2][16*88] = 22KB, total
// attn LDS 38.5KB, still 4 blocks/CU.
// ---------------------------------------------------------------------------

typedef __bf16 bf16;
typedef __bf16 bf16x8 __attribute__((ext_vector_type(8)));
typedef __bf16 bf16x4 __attribute__((ext_vector_type(4)));
typedef float f32x4 __attribute__((ext_vector_type(4)));

#define LOG2E 1.4426950408889634f
// Schraudolph: p = exp(s/8 - 16) = 2^t, bits(p) ~= int(2^23*(t + 126.9427)).
// Q pre-scaled by QSCALE so QK-MFMA emits t' = 2^23*t; acc seeded with
// SEXP_SEED. t' in [7.7e8, 1.1e9]; masked entries t'=0 -> p=+0.0 exactly.
#define QSCALE (0.125f * LOG2E * 8388608.0f)
#define SEXP_SEED ((126.94269504f - 16.0f * LOG2E) * 8388608.0f)

__device__ __forceinline__ void async16(const void* g, void* l) {
  __builtin_amdgcn_global_load_lds(
      (const __attribute__((address_space(1))) void*)g,
      (__attribute__((address_space(3))) void*)l, 16, 0, 0);
}

#define MFMA16(a, b, c) __builtin_amdgcn_mfma_f32_16x16x32_bf16(a, b, c, 0, 0, 0)

// ---------------------------------------------------------------------------
// fused fp32 -> bf16 cast for x + 4 weights + cos/sin float2 fusion.
// ---------------------------------------------------------------------------
__global__ void cast_all_kernel(const float* __restrict__ x,
                                const float* __restrict__ wq,
                                const float* __restrict__ wk,
                                const float* __restrict__ wv,
                                const float* __restrict__ wo,
                                const float* __restrict__ cosT,
                                const float* __restrict__ sinT,
                                bf16* __restrict__ xb, bf16* __restrict__ wb,
                                float2* __restrict__ csT) {
  int i = blockIdx.x * blockDim.x + threadIdx.x;
  if (i >= 3145728) {  // cos/sin fusion: 65536 pairs
    int j = i - 3145728;
    float2 cs;
    cs.x = cosT[j];
    cs.y = sinT[j];
    csT[j] = cs;
    return;
  }
  const float* src;
  bf16* dst;
  long o;
  if (i < 2097152) {
    src = x; dst = xb; o = i;
  } else {
    long j = i - 2097152;
    int w = (int)(j >> 18);
    o = j & 262143;
    src = (w == 0) ? wq : (w == 1) ? wk : (w == 2) ? wv : wo;
    dst = wb + (long)w * 1048576;
  }
  float4 v = reinterpret_cast<const float4*>(src)[o];
  bf16x4 out;
  out.x = (bf16)v.x; out.y = (bf16)v.y; out.z = (bf16)v.z; out.w = (bf16)v.w;
  *reinterpret_cast<bf16x4*>(dst + o * 4) = out;
}

// ---------------------------------------------------------------------------
// Generic bt-GEMM body: C[m][n] = sum_k A[m][k]*B[n][k].  TM x TN block tile.
// R13: BK=64, single LDS buffer.  Per K-step: stage, barrier, 2 halves of
// {ds_read_b128 + MFMA}, barrier.  32 MFMA per barrier-pair at TN=128.
// LDS layout: row stride 64 elem (128B); 16B chunk c of row r stored at slot
// (c ^ (r&7)) -> b128 fragment reads spread uniformly over all 32 banks;
// global_load_lds dst stays linear (wave-uniform base + lane*16), the global
// SOURCE col is pre-swizzled (m173 pattern).
// EPI 0: QK + RoPE epilogue (bn<8 = Q half, Schraudolph pre-scale).
// EPI 1: bf16 V^T (b,h,d,s).  EPI 2: fp32 row-major (M,N).
// ---------------------------------------------------------------------------
template <int EPI, int TM, int TN>
__device__ __forceinline__ void gemm_dev(const bf16* __restrict__ A,
                                         const bf16* __restrict__ B,
                                         void* __restrict__ C, int N, int K,
                                         int bm, int bn, bf16* As, bf16* Bs,
                                         const float2* __restrict__ csT) {
  constexpr int WM = TM / 64;
  constexpr int WN = 4 / WM;
  constexpr int CW = TN / WN;
  constexpr int NT = CW / 16;
  constexpr int ROUNDS = (TM + TN) / 32;  // (TM+TN)*8 chunks / 256 threads
  const int tid = threadIdx.x;
  const int wid = tid >> 6, lane = tid & 63;
  const int quad = lane >> 4, l15 = lane & 15;
  const int waveM = wid / WN, waveN = wid % WN;

  f32x4 acc[4][NT] = {};
  const bf16* Ag = A + (long)bm * TM * K;
  const bf16* Bg = B + (long)bn * TN * K;

  for (int k0 = 0; k0 < K; k0 += 64) {
    // stage BK=64 tiles of A and B (chunk ci -> LDS byte ci*16, linear;
    // logical col chunk of slot s in row r is s^(r&7) -> pre-swizzled src)
#pragma unroll
    for (int ri = 0; ri < ROUNDS; ++ri) {
      int ci = ri * 256 + tid;
      int gb = ri * 256 + (wid << 6);  // wave-uniform
      bool isA = gb < TM * 8;          // A = TM*8 chunks (multiple of 64)
      int cl = isA ? ci : ci - TM * 8;
      int r = cl >> 3;
      int col = ((cl & 7) ^ (r & 7)) << 3;
      const bf16* src = (isA ? Ag : Bg) + (long)r * K + k0 + col;
      char* dst = isA ? ((char*)As + (long)ci * 16)
                      : ((char*)Bs + (long)(ci - TM * 8) * 16);
      async16(src, dst);
    }
    __syncthreads();
#pragma unroll
    for (int kk = 0; kk < 2; ++kk) {
      bf16x8 af[4], bfr[NT];
#pragma unroll
      for (int t = 0; t < 4; ++t) {
        int rowA = waveM * 64 + t * 16 + l15;
        af[t] = *(const bf16x8*)(As + rowA * 64 +
                                 ((((kk << 2) + quad) ^ (rowA & 7)) << 3));
      }
#pragma unroll
      for (int t = 0; t < NT; ++t) {
        int rowB = waveN * CW + t * 16 + l15;
        bfr[t] = *(const bf16x8*)(Bs + rowB * 64 +
                                  ((((kk << 2) + quad) ^ (rowB & 7)) << 3));
      }
#pragma unroll
      for (int mt = 0; mt < 4; ++mt)
#pragma unroll
        for (int nt = 0; nt < NT; ++nt)
          acc[mt][nt] = MFMA16(af[mt], bfr[nt], acc[mt][nt]);
    }
    if (k0 + 64 < K) __syncthreads();  // protect buffer reuse
  }

  const float qsc = (EPI == 0 && bn < 8) ? QSCALE : 1.0f;
#pragma unroll
  for (int mt = 0; mt < 4; ++mt)
#pragma unroll
    for (int nt = 0; nt < NT; ++nt)
#pragma unroll
      for (int r = 0; r < 4; ++r) {
        int row = bm * TM + waveM * 64 + mt * 16 + quad * 4 + r;
        int col = bn * TN + waveN * CW + nt * 16 + l15;
        float v = acc[mt][nt][r];
        if (EPI == 0) {
          // RoPE: col pairs (even,odd) live in adjacent lanes
          float pr = __shfl_xor(v, 1);
          int d = col & 63;
          float2 cs = csT[(row & 2047) * 32 + (d >> 1)];
          float o =
              (col & 1) ? (v * cs.x + pr * cs.y) : (v * cs.x - pr * cs.y);
          o *= qsc;
          long off = (long)(col >> 10) * 8388608 +
                     (long)(((row >> 11) << 4) + ((col >> 6) & 15)) * 131072 +
                     (long)(row & 2047) * 64 + d;
          ((bf16*)C)[off] = (bf16)o;
        } else if (EPI == 1) {
          long off = (long)(col >> 11) * 2097152 + (long)row * 2048 +
                     (col & 2047);
          ((bf16*)C)[off] = (bf16)v;
        } else {
          ((float*)C)[(long)row * N + col] = v;
        }
      }
}

// Merged Q/K projection (+RoPE) and V projection (V^T) in one launch.
// RANGE role split: ids [0,1024) = QK, ids [1024,1536) = V.
// Per-role XCD-chunked swizzle (XCD = blockIdx % 8) keeps shared operand
// panels in one XCD's L2 (R9 verified: FETCH 93.5 -> 58.5 MB).
__global__ __launch_bounds__(256) void gemm_qkv(const bf16* __restrict__ xb,
                                                const bf16* __restrict__ wqk,
                                                const bf16* __restrict__ wv,
                                                bf16* __restrict__ QK,
                                                bf16* __restrict__ VT,
                                                const float2* __restrict__ csT) {
  __shared__ __align__(16) bf16 As[128 * 64];
  __shared__ __align__(16) bf16 Bs[128 * 64];
  int p = blockIdx.x;
  if (p >= 1024) {
    // V: A=w_v (M=1024, 8 tiles), B=x (N=8192, 64 tiles).  bn-major logical
    // order: each XCD chunk = 8 x-panels (2MB) x all bm (w_v 2MB L2-resident).
    int pv = p - 1024;                    // [0,512)
    int lv = (pv & 7) * 64 + (pv >> 3);   // XCD-chunked, bijective
    gemm_dev<1, 128, 128>(wv, xb, VT, 8192, 1024, lv & 7, lv >> 3, As, Bs,
                          nullptr);
  } else {
    // QK: A=x (M=8192, 64 tiles), B=[w_q;w_k] (N=2048, 16 tiles).  bm-major:
    // each XCD chunk = 8 A-panels x all bn (w_qk 4MB streams through L2).
    int l = (p & 7) * 128 + (p >> 3);
    gemm_dev<0, 128, 128>(xb, wqk, QK, 2048, 1024, l >> 4, l & 15, As, Bs,
                          csT);
  }
}

// Output projection: A=attn (M=8192, 64 tiles), B=w_o (N=1024, 16 tiles),
// 128x64 tiles -> 1024 blocks (~5 blocks/CU).  24KB LDS.  XCD-chunked
// bijective swizzle (R15; occupancy change measured null vs 128x128 --
// kept to avoid instantiation churn).
__global__ __launch_bounds__(256) void gemm_out(const bf16* __restrict__ A,
                                                const bf16* __restrict__ B,
                                                float* __restrict__ C) {
  __shared__ __align__(16) bf16 As[128 * 64];
  __shared__ __align__(16) bf16 Bs[64 * 64];
  int p = blockIdx.x;
  int l = (p & 7) * 128 + (p >> 3);  // XCD-chunked, bijective (1024 % 8 == 0)
  gemm_dev<2, 128, 64>(A, B, C, 1024, 1024, l >> 4, l & 15, As, Bs, nullptr);
}

// ---------------------------------------------------------------------------
// Flash attention, causal, paired q-tiles {p, 31-p}, single-buffer staging.
// Schraudolph P: QK MFMA seeded with SEXP_SEED emits t'; bf16 P bits =
// int(t')>>16.  l via MFMA with ones fragment -> accL rows align with accO
// rows (no shuffles).
// R16: attn_step2 fuses both q-tiles for kt<=q0t (shared kf/vf fragments,
// one fence).  attn_step handles the single-tile tail kt>q0t.
// ---------------------------------------------------------------------------
__device__ __forceinline__ void pack_row(const f32x4& s, bf16* Pw, int l15,
                                         int mt, int quad) {
  int i0 = (int)s[0], i1 = (int)s[1], i2 = (int)s[2], i3 = (int)s[3];
  uint2 pk;
  pk.x = __builtin_amdgcn_perm((unsigned)i1, (unsigned)i0, 0x07060302u);
  pk.y = __builtin_amdgcn_perm((unsigned)i3, (unsigned)i2, 0x07060302u);
  *(uint2*)(Pw + l15 * 88 + mt * 16 + quad * 4) = pk;
}

__device__ __forceinline__ void attn_step(const bf16* Ks, const bf16* Vs,
                                          bf16* Pw, const bf16x8* qf,
                                          const bf16x8 ones, f32x4* accO,
                                          f32x4& accL, int quad, int l15,
                                          int qloc, bool diag) {
  const int sw = l15 & 7;
  const f32x4 seedv = {SEXP_SEED, SEXP_SEED, SEXP_SEED, SEXP_SEED};
  f32x4 sacc[4] = {seedv, seedv, seedv, seedv};
#pragma unroll
  for (int mt = 0; mt < 4; ++mt)
#pragma unroll
    for (int kk = 0; kk < 2; ++kk) {
      bf16x8 kf = *(const bf16x8*)(Ks + (mt * 16 + l15) * 64 +
                                   ((((kk << 2) + quad) ^ sw) << 3));
      sacc[mt] = MFMA16(kf, qf[kk], sacc[mt]);
    }
  // D layout: lane l15 = q (col), key_local = mt*16 + quad*4 + r (row)
  if (diag) {  // wave-uniform: mask -> t'=0 -> p=+0.0 exactly
#pragma unroll
    for (int mt = 0; mt < 4; ++mt)
#pragma unroll
      for (int r = 0; r < 4; ++r)
        if ((mt * 16 + quad * 4 + r) > qloc) sacc[mt][r] = 0.0f;
  }
#pragma unroll
  for (int mt = 0; mt < 4; ++mt) pack_row(sacc[mt], Pw, l15, mt, quad);
  asm volatile("s_waitcnt lgkmcnt(0)" ::: "memory");  // wave-private RAW fence
  bf16x8 pfr[2];
#pragma unroll
  for (int kk = 0; kk < 2; ++kk)
    pfr[kk] = *(const bf16x8*)(Pw + l15 * 88 + kk * 32 + quad * 8);
#pragma unroll
  for (int nt = 0; nt < 4; ++nt)
#pragma unroll
    for (int kk = 0; kk < 2; ++kk) {
      bf16x8 vf = *(const bf16x8*)(Vs + (nt * 16 + l15) * 64 +
                                   ((((kk << 2) + quad) ^ sw) << 3));
      accO[nt] = MFMA16(pfr[kk], vf, accO[nt]);
    }
#pragma unroll
  for (int kk = 0; kk < 2; ++kk)
    accL = MFMA16(pfr[kk], ones, accL);  // l[q=quad*4+r] = accL[r]
}

// Fused: both q-tiles share every kf/vf fragment; one fence per iteration.
// q1 is never diagonal in the fused range (kt <= q0t < q1t).
__device__ __forceinline__ void attn_step2(
    const bf16* Ks, const bf16* Vs, bf16* Pw1, bf16* Pw0, const bf16x8* qf1,
    const bf16x8* qf0, const bf16x8 ones, f32x4* acc1, f32x4* acc0,
    f32x4& accL1, f32x4& accL0, int quad, int l15, int qloc, bool diag0) {
  const int sw = l15 & 7;
  const f32x4 seedv = {SEXP_SEED, SEXP_SEED, SEXP_SEED, SEXP_SEED};
#pragma unroll
  for (int mt = 0; mt < 4; ++mt) {
    f32x4 s1 = seedv, s0 = seedv;
#pragma unroll
    for (int kk = 0; kk < 2; ++kk) {
      bf16x8 kf = *(const bf16x8*)(Ks + (mt * 16 + l15) * 64 +
                                   ((((kk << 2) + quad) ^ sw) << 3));
      s1 = MFMA16(kf, qf1[kk], s1);
      s0 = MFMA16(kf, qf0[kk], s0);
    }
    if (diag0) {
#pragma unroll
      for (int r = 0; r < 4; ++r)
        if ((mt * 16 + quad * 4 + r) > qloc) s0[r] = 0.0f;
    }
    pack_row(s1, Pw1, l15, mt, quad);
    pack_row(s0, Pw0, l15, mt, quad);
  }
  asm volatile("s_waitcnt lgkmcnt(0)" ::: "memory");  // ONE fence for both
  bf16x8 pf1[2], pf0[2];
#pragma unroll
  for (int kk = 0; kk < 2; ++kk) {
    pf1[kk] = *(const bf16x8*)(Pw1 + l15 * 88 + kk * 32 + quad * 8);
    pf0[kk] = *(const bf16x8*)(Pw0 + l15 * 88 + kk * 32 + quad * 8);
  }
#pragma unroll
  for (int nt = 0; nt < 4; ++nt)
#pragma unroll
    for (int kk = 0; kk < 2; ++kk) {
      bf16x8 vf = *(const bf16x8*)(Vs + (nt * 16 + l15) * 64 +
                                   ((((kk << 2) + quad) ^ sw) << 3));
      acc1[nt] = MFMA16(pf1[kk], vf, acc1[nt]);
      acc0[nt] = MFMA16(pf0[kk], vf, acc0[nt]);
    }
#pragma unroll
  for (int kk = 0; kk < 2; ++kk) {
    accL1 = MFMA16(pf1[kk], ones, accL1);
    accL0 = MFMA16(pf0[kk], ones, accL0);
  }
}

// 1D grid of 1024 with bh-grouped XCD swizzle -- XCD c (= blockIdx%8)
// serves bh in [8c, 8c+8), so each XCD's K/V working set is ~4MB (L2-fit)
// instead of all 64 heads (64MB).  Pure bijective remap, compute unchanged.
__global__ __launch_bounds__(256, 4) void attn_kernel(
    const bf16* __restrict__ Q, const bf16* __restrict__ Kg,
    const bf16* __restrict__ VT, bf16* __restrict__ Out) {
  __shared__ __align__(16) bf16 Ks[64 * 64];
  __shared__ __align__(16) bf16 Vs[64 * 64];
  __shared__ __align__(16) bf16 Ps[4][2][16 * 88];
  const int tid = threadIdx.x, wid = tid >> 6, lane = tid & 63;
  const int quad = lane >> 4, l15 = lane & 15;
  const int id = blockIdx.x;
  const int p = (id >> 3) & 15;             // q-pair index [0,16)
  const int bh = (id & 7) * 8 + (id >> 7);  // head-batch, XCD-grouped
  const int q0t = p, q1t = 31 - p;
  const bf16* Qb = Q + (long)bh * 131072;
  const bf16* Kb = Kg + (long)bh * 131072;
  const bf16* Vb = VT + (long)bh * 131072;
  bf16* Pw1 = &Ps[wid][0][0];
  bf16* Pw0 = &Ps[wid][1][0];
  const int qloc = wid * 16 + l15;

  bf16x8 ones;
#pragma unroll
  for (int j = 0; j < 8; ++j) ones[j] = (bf16)1.0f;

  bf16x8 qf0[2], qf1[2];
#pragma unroll
  for (int kk = 0; kk < 2; ++kk) {
    qf0[kk] = *(const bf16x8*)(Qb + (long)(q0t * 64 + qloc) * 64 + kk * 32 +
                               quad * 8);
    qf1[kk] = *(const bf16x8*)(Qb + (long)(q1t * 64 + qloc) * 64 + kk * 32 +
                               quad * 8);
  }
  f32x4 acc0[4] = {}, acc1[4] = {};
  f32x4 accL0 = {}, accL1 = {};

  for (int kt = 0; kt <= q1t; ++kt) {
#pragma unroll
    for (int it = 0; it < 2; ++it) {
      int chunk = it * 256 + tid;
      int r = chunk >> 3;
      int c = (((chunk & 7) ^ (r & 7)) << 3);
      int ldsbase = (it * 256 + wid * 64) * 16;
      async16(Kb + (long)(kt * 64 + r) * 64 + c, (char*)Ks + ldsbase);
      async16(Vb + (long)r * 2048 + kt * 64 + c, (char*)Vs + ldsbase);
    }
    __syncthreads();
    if (kt <= q0t)
      attn_step2(Ks, Vs, Pw1, Pw0, qf1, qf0, ones, acc1, acc0, accL1, accL0,
                 quad, l15, qloc, kt == q0t);
    else
      attn_step(Ks, Vs, Pw1, qf1, ones, acc1, accL1, quad, l15, qloc,
                kt == q1t);
    __syncthreads();
  }

  // epilogue: accL rows already aligned with accO rows -> no shuffles
  const int b = bh >> 4, h = bh & 15;
#pragma unroll
  for (int r = 0; r < 4; ++r) {
    float lr0 = 1.0f / accL0[r];
    float lr1 = 1.0f / accL1[r];
#pragma unroll
    for (int nt = 0; nt < 4; ++nt) {
      int d = h * 64 + nt * 16 + l15;
      int qg0 = q0t * 64 + wid * 16 + quad * 4 + r;
      int qg1 = q1t * 64 + wid * 16 + quad * 4 + r;
      Out[(long)(b * 2048 + qg0) * 1024 + d] = (bf16)(acc0[nt][r] * lr0);
      Out[(long)(b * 2048 + qg1) * 1024 + d] = (bf16)(acc1[nt][r] * lr1);
    }
  }
}

// ---------------------------------------------------------------------------
// Workspace layout (bytes):
//   xb  @ 0         (16,777,216)  -- reused as attn output
//   wqb @ 16777216  (2 MiB) \  [w_q; w_k] contiguous for fused QK GEMM,
//   wkb @ 18874368  (2 MiB) |  [w_v; w_o] follow for fused cast
//   wvb @ 20971520  (2 MiB) |
//   wob @ 23068672  (2 MiB) /
//   Qb  @ 25165824  (16,777,216)  (b,h,s,d) bf16, pre-scaled by QSCALE
//   Kb  @ 41943040  (16,777,216)  (b,h,s,d) bf16
//   VTb @ 58720256  (16,777,216)  (b,h,d,s) bf16
//   csT @ 75497472  (   524,288)  fused cos/sin float2 table
// ---------------------------------------------------------------------------
extern "C" void kernel_launch(void* const* d_in, const int* in_sizes, int n_in,
                              void* d_out, int out_size, void* d_ws,
                              size_t ws_size, hipStream_t stream) {
  const float* x = (const float*)d_in[0];
  const float* w_q = (const float*)d_in[1];
  const float* w_k = (const float*)d_in[2];
  const float* w_v = (const float*)d_in[3];
  const float* w_o = (const float*)d_in[4];
  const float* cosT = (const float*)d_in[5];
  const float* sinT = (const float*)d_in[6];

  char* ws = (char*)d_ws;
  bf16* xb = (bf16*)(ws + 0);
  bf16* wqb = (bf16*)(ws + 16777216);
  bf16* wvb = (bf16*)(ws + 20971520);
  bf16* wob = (bf16*)(ws + 23068672);
  bf16* Qb = (bf16*)(ws + 25165824);
  bf16* Kb = (bf16*)(ws + 41943040);
  bf16* VTb = (bf16*)(ws + 58720256);
  float2* csT = (float2*)(ws + 75497472);
  bf16* attnb = xb;

  // fused cast: x + all 4 weights + cos/sin float2 fusion in one launch
  cast_all_kernel<<<12544, 256, 0, stream>>>(x, w_q, w_k, w_v, w_o, cosT,
                                             sinT, xb, wqb, csT);

  // merged Q/K (+RoPE, Schraudolph pre-scale) and V^T projections.
  // BK=64 single-buffer; 1024 QK + 512 V blocks (128x128), XCD chunks.
  gemm_qkv<<<1536, 256, 0, stream>>>(xb, wqb, wvb, Qb, VTb, csT);

  // balanced causal flash attention -> (b,s,e) bf16 (fused dual-tile steps)
  attn_kernel<<<1024, 256, 0, stream>>>(Qb, Kb, VTb, attnb);

  // output projection -> fp32 (128x64 tiles, 1024 blocks, XCD chunks)
  gemm_out<<<1024, 256, 0, stream>>>(attnb, wob, (float*)d_out);
}

// Round 9
// 235.417 us; speedup vs baseline: 1.0532x; 1.0532x over previous
//
#include <hip/hip_runtime.h>
#include <hip/hip_bf16.h>

// ---------------------------------------------------------------------------
// CausalMultiHeadedSelfAttention on gfx950.
// R17 = R13-exact revert (best measured: 236.0us).  Session ledger:
//   WINS: R11 V-tile 128x128 (+16% qkv), R13 BK=64 single-buffer (+13% qkv)
//         -- both "more MFMA per barrier-pair, no added live state".
//   LOSSES (all reverted): R9 GEMM dbuf (null), R10 counted-vmcnt 3-buf
//         (-23%, compiler re-drains + runtime idx VALU tax), R12 attn K/V
//         dbuf (+10us), R14 gemm_dev signature change (rule-#19 qkv
//         perturbation -20%) + split-K atomics, R15 gemm_out 128x64@1024
//         (null: gemm_out insensitive to occupancy/tile/BK -- 3 nulls),
//         R16 attn dual-tile fusion solo (+9us: doubled live state under
//         launch_bounds(256,4) outweighs halved kf/vf reads).
// attn bracketed by two symmetric regressions -> local optimum of this
// structure.  Remaining unexploited lever: 8-phase 256^2 qkv port.
// ---------------------------------------------------------------------------

typedef __bf16 bf16;
typedef __bf16 bf16x8 __attribute__((ext_vector_type(8)));
typedef __bf16 bf16x4 __attribute__((ext_vector_type(4)));
typedef float f32x4 __attribute__((ext_vector_type(4)));

#define LOG2E 1.4426950408889634f
// Schraudolph: p = exp(s/8 - 16) = 2^t, bits(p) ~= int(2^23*(t + 126.9427)).
// Q pre-scaled by QSCALE so QK-MFMA emits t' = 2^23*t; acc seeded with
// SEXP_SEED. t' in [7.7e8, 1.1e9]; masked entries t'=0 -> p=+0.0 exactly.
#define QSCALE (0.125f * LOG2E * 8388608.0f)
#define SEXP_SEED ((126.94269504f - 16.0f * LOG2E) * 8388608.0f)

__device__ __forceinline__ void async16(const void* g, void* l) {
  __builtin_amdgcn_global_load_lds(
      (const __attribute__((address_space(1))) void*)g,
      (__attribute__((address_space(3))) void*)l, 16, 0, 0);
}

#define MFMA16(a, b, c) __builtin_amdgcn_mfma_f32_16x16x32_bf16(a, b, c, 0, 0, 0)

// ---------------------------------------------------------------------------
// fused fp32 -> bf16 cast for x + 4 weights + cos/sin float2 fusion.
// ---------------------------------------------------------------------------
__global__ void cast_all_kernel(const float* __restrict__ x,
                                const float* __restrict__ wq,
                                const float* __restrict__ wk,
                                const float* __restrict__ wv,
                                const float* __restrict__ wo,
                                const float* __restrict__ cosT,
                                const float* __restrict__ sinT,
                                bf16* __restrict__ xb, bf16* __restrict__ wb,
                                float2* __restrict__ csT) {
  int i = blockIdx.x * blockDim.x + threadIdx.x;
  if (i >= 3145728) {  // cos/sin fusion: 65536 pairs
    int j = i - 3145728;
    float2 cs;
    cs.x = cosT[j];
    cs.y = sinT[j];
    csT[j] = cs;
    return;
  }
  const float* src;
  bf16* dst;
  long o;
  if (i < 2097152) {
    src = x; dst = xb; o = i;
  } else {
    long j = i - 2097152;
    int w = (int)(j >> 18);
    o = j & 262143;
    src = (w == 0) ? wq : (w == 1) ? wk : (w == 2) ? wv : wo;
    dst = wb + (long)w * 1048576;
  }
  float4 v = reinterpret_cast<const float4*>(src)[o];
  bf16x4 out;
  out.x = (bf16)v.x; out.y = (bf16)v.y; out.z = (bf16)v.z; out.w = (bf16)v.w;
  *reinterpret_cast<bf16x4*>(dst + o * 4) = out;
}

// ---------------------------------------------------------------------------
// Generic bt-GEMM body: C[m][n] = sum_k A[m][k]*B[n][k].  TM x TN block tile.
// R13: BK=64, single LDS buffer.  Per K-step: stage, barrier, 2 halves of
// {ds_read_b128 + MFMA}, barrier.  32 MFMA per barrier-pair at TN=128.
// LDS layout: row stride 64 elem (128B); 16B chunk c of row r stored at slot
// (c ^ (r&7)) -> b128 fragment reads spread uniformly over all 32 banks;
// global_load_lds dst stays linear (wave-uniform base + lane*16), the global
// SOURCE col is pre-swizzled (m173 pattern).
// EPI 0: QK + RoPE epilogue (bn<8 = Q half, Schraudolph pre-scale).
// EPI 1: bf16 V^T (b,h,d,s).  EPI 2: fp32 row-major (M,N).
// ---------------------------------------------------------------------------
template <int EPI, int TM, int TN>
__device__ __forceinline__ void gemm_dev(const bf16* __restrict__ A,
                                         const bf16* __restrict__ B,
                                         void* __restrict__ C, int N, int K,
                                         int bm, int bn, bf16* As, bf16* Bs,
                                         const float2* __restrict__ csT) {
  constexpr int WM = TM / 64;
  constexpr int WN = 4 / WM;
  constexpr int CW = TN / WN;
  constexpr int NT = CW / 16;
  constexpr int ROUNDS = (TM + TN) / 32;  // (TM+TN)*8 chunks / 256 threads
  const int tid = threadIdx.x;
  const int wid = tid >> 6, lane = tid & 63;
  const int quad = lane >> 4, l15 = lane & 15;
  const int waveM = wid / WN, waveN = wid % WN;

  f32x4 acc[4][NT] = {};
  const bf16* Ag = A + (long)bm * TM * K;
  const bf16* Bg = B + (long)bn * TN * K;

  for (int k0 = 0; k0 < K; k0 += 64) {
    // stage BK=64 tiles of A and B (chunk ci -> LDS byte ci*16, linear;
    // logical col chunk of slot s in row r is s^(r&7) -> pre-swizzled src)
#pragma unroll
    for (int ri = 0; ri < ROUNDS; ++ri) {
      int ci = ri * 256 + tid;
      int gb = ri * 256 + (wid << 6);  // wave-uniform
      bool isA = gb < TM * 8;          // A = TM*8 chunks (multiple of 64)
      int cl = isA ? ci : ci - TM * 8;
      int r = cl >> 3;
      int col = ((cl & 7) ^ (r & 7)) << 3;
      const bf16* src = (isA ? Ag : Bg) + (long)r * K + k0 + col;
      char* dst = isA ? ((char*)As + (long)ci * 16)
                      : ((char*)Bs + (long)(ci - TM * 8) * 16);
      async16(src, dst);
    }
    __syncthreads();
#pragma unroll
    for (int kk = 0; kk < 2; ++kk) {
      bf16x8 af[4], bfr[NT];
#pragma unroll
      for (int t = 0; t < 4; ++t) {
        int rowA = waveM * 64 + t * 16 + l15;
        af[t] = *(const bf16x8*)(As + rowA * 64 +
                                 ((((kk << 2) + quad) ^ (rowA & 7)) << 3));
      }
#pragma unroll
      for (int t = 0; t < NT; ++t) {
        int rowB = waveN * CW + t * 16 + l15;
        bfr[t] = *(const bf16x8*)(Bs + rowB * 64 +
                                  ((((kk << 2) + quad) ^ (rowB & 7)) << 3));
      }
#pragma unroll
      for (int mt = 0; mt < 4; ++mt)
#pragma unroll
        for (int nt = 0; nt < NT; ++nt)
          acc[mt][nt] = MFMA16(af[mt], bfr[nt], acc[mt][nt]);
    }
    if (k0 + 64 < K) __syncthreads();  // protect buffer reuse
  }

  const float qsc = (EPI == 0 && bn < 8) ? QSCALE : 1.0f;
#pragma unroll
  for (int mt = 0; mt < 4; ++mt)
#pragma unroll
    for (int nt = 0; nt < NT; ++nt)
#pragma unroll
      for (int r = 0; r < 4; ++r) {
        int row = bm * TM + waveM * 64 + mt * 16 + quad * 4 + r;
        int col = bn * TN + waveN * CW + nt * 16 + l15;
        float v = acc[mt][nt][r];
        if (EPI == 0) {
          // RoPE: col pairs (even,odd) live in adjacent lanes
          float pr = __shfl_xor(v, 1);
          int d = col & 63;
          float2 cs = csT[(row & 2047) * 32 + (d >> 1)];
          float o =
              (col & 1) ? (v * cs.x + pr * cs.y) : (v * cs.x - pr * cs.y);
          o *= qsc;
          long off = (long)(col >> 10) * 8388608 +
                     (long)(((row >> 11) << 4) + ((col >> 6) & 15)) * 131072 +
                     (long)(row & 2047) * 64 + d;
          ((bf16*)C)[off] = (bf16)o;
        } else if (EPI == 1) {
          long off = (long)(col >> 11) * 2097152 + (long)row * 2048 +
                     (col & 2047);
          ((bf16*)C)[off] = (bf16)v;
        } else {
          ((float*)C)[(long)row * N + col] = v;
        }
      }
}

// Merged Q/K projection (+RoPE) and V projection (V^T) in one launch.
// RANGE role split: ids [0,1024) = QK, ids [1024,1536) = V.
// Per-role XCD-chunked swizzle (XCD = blockIdx % 8) keeps shared operand
// panels in one XCD's L2 (R9 verified: FETCH 93.5 -> 58.5 MB).
__global__ __launch_bounds__(256) void gemm_qkv(const bf16* __restrict__ xb,
                                                const bf16* __restrict__ wqk,
                                                const bf16* __restrict__ wv,
                                                bf16* __restrict__ QK,
                                                bf16* __restrict__ VT,
                                                const float2* __restrict__ csT) {
  __shared__ __align__(16) bf16 As[128 * 64];
  __shared__ __align__(16) bf16 Bs[128 * 64];
  int p = blockIdx.x;
  if (p >= 1024) {
    // V: A=w_v (M=1024, 8 tiles), B=x (N=8192, 64 tiles).  bn-major logical
    // order: each XCD chunk = 8 x-panels (2MB) x all bm (w_v 2MB L2-resident).
    int pv = p - 1024;                    // [0,512)
    int lv = (pv & 7) * 64 + (pv >> 3);   // XCD-chunked, bijective
    gemm_dev<1, 128, 128>(wv, xb, VT, 8192, 1024, lv & 7, lv >> 3, As, Bs,
                          nullptr);
  } else {
    // QK: A=x (M=8192, 64 tiles), B=[w_q;w_k] (N=2048, 16 tiles).  bm-major:
    // each XCD chunk = 8 A-panels x all bn (w_qk 4MB streams through L2).
    int l = (p & 7) * 128 + (p >> 3);
    gemm_dev<0, 128, 128>(xb, wqk, QK, 2048, 1024, l >> 4, l & 15, As, Bs,
                          csT);
  }
}

// Output projection: A=attn (M=8192, 64 tiles), B=w_o (N=1024, 8 tiles),
// 128x128 tiles -> fp32.  512 blocks, XCD-chunked (each XCD: 8 contiguous
// A-panels x all 8 bn; w_o 2MB L2-resident).  Measured insensitive to
// tile/BK/occupancy (R13/R15 nulls) -- keep the R13 config.
__global__ __launch_bounds__(256) void gemm_out(const bf16* __restrict__ A,
                                                const bf16* __restrict__ B,
                                                float* __restrict__ C) {
  __shared__ __align__(16) bf16 As[128 * 64];
  __shared__ __align__(16) bf16 Bs[128 * 64];
  int p = blockIdx.x;
  int l = (p & 7) * 64 + (p >> 3);
  gemm_dev<2, 128, 128>(A, B, C, 1024, 1024, l >> 3, l & 7, As, Bs, nullptr);
}

// ---------------------------------------------------------------------------
// Flash attention, causal, paired q-tiles {p, 31-p}, R5/R11 single-buffer
// structure (best measured; R12 dbuf and R16 fusion both regressed ~+9us --
// bracketed local optimum).  Schraudolph P: QK MFMA seeded with SEXP_SEED
// emits t'; bf16 P bits = int(t')>>16.  l via MFMA with ones fragment ->
// accL rows align with accO rows (no shuffles).
// ---------------------------------------------------------------------------
__device__ __forceinline__ void attn_step(const bf16* Ks, const bf16* Vs,
                                          bf16* Pw, const bf16x8* qf,
                                          const bf16x8 ones, f32x4* accO,
                                          f32x4& accL, int quad, int l15,
                                          int qloc, bool diag) {
  const int sw = l15 & 7;
  const f32x4 seedv = {SEXP_SEED, SEXP_SEED, SEXP_SEED, SEXP_SEED};
  f32x4 sacc[4] = {seedv, seedv, seedv, seedv};
#pragma unroll
  for (int mt = 0; mt < 4; ++mt)
#pragma unroll
    for (int kk = 0; kk < 2; ++kk) {
      bf16x8 kf = *(const bf16x8*)(Ks + (mt * 16 + l15) * 64 +
                                   ((((kk << 2) + quad) ^ sw) << 3));
      sacc[mt] = MFMA16(kf, qf[kk], sacc[mt]);
    }
  // D layout: lane l15 = q (col), key_local = mt*16 + quad*4 + r (row)
  if (diag) {  // wave-uniform: mask -> t'=0 -> p=+0.0 exactly
#pragma unroll
    for (int mt = 0; mt < 4; ++mt)
#pragma unroll
      for (int r = 0; r < 4; ++r)
        if ((mt * 16 + quad * 4 + r) > qloc) sacc[mt][r] = 0.0f;
  }
  // Schraudolph exp2 + bf16 pack: bits = int(t'); bf16 = bits>>16
#pragma unroll
  for (int mt = 0; mt < 4; ++mt) {
    int i0 = (int)sacc[mt][0], i1 = (int)sacc[mt][1];
    int i2 = (int)sacc[mt][2], i3 = (int)sacc[mt][3];
    uint2 pk;
    pk.x = __builtin_amdgcn_perm((unsigned)i1, (unsigned)i0, 0x07060302u);
    pk.y = __builtin_amdgcn_perm((unsigned)i3, (unsigned)i2, 0x07060302u);
    *(uint2*)(Pw + l15 * 88 + mt * 16 + quad * 4) = pk;
  }
  asm volatile("s_waitcnt lgkmcnt(0)" ::: "memory");  // wave-private RAW fence
  bf16x8 pfr[2];
#pragma unroll
  for (int kk = 0; kk < 2; ++kk)
    pfr[kk] = *(const bf16x8*)(Pw + l15 * 88 + kk * 32 + quad * 8);
#pragma unroll
  for (int nt = 0; nt < 4; ++nt)
#pragma unroll
    for (int kk = 0; kk < 2; ++kk) {
      bf16x8 vf = *(const bf16x8*)(Vs + (nt * 16 + l15) * 64 +
                                   ((((kk << 2) + quad) ^ sw) << 3));
      accO[nt] = MFMA16(pfr[kk], vf, accO[nt]);
    }
#pragma unroll
  for (int kk = 0; kk < 2; ++kk)
    accL = MFMA16(pfr[kk], ones, accL);  // l[q=quad*4+r] = accL[r]
}

// 1D grid of 1024 with bh-grouped XCD swizzle -- XCD c (= blockIdx%8)
// serves bh in [8c, 8c+8), so each XCD's K/V working set is ~4MB (L2-fit)
// instead of all 64 heads (64MB).  Pure bijective remap, compute unchanged.
__global__ __launch_bounds__(256, 4) void attn_kernel(
    const bf16* __restrict__ Q, const bf16* __restrict__ Kg,
    const bf16* __restrict__ VT, bf16* __restrict__ Out) {
  __shared__ __align__(16) bf16 Ks[64 * 64];
  __shared__ __align__(16) bf16 Vs[64 * 64];
  __shared__ __align__(16) bf16 Ps[4][16 * 88];
  const int tid = threadIdx.x, wid = tid >> 6, lane = tid & 63;
  const int quad = lane >> 4, l15 = lane & 15;
  const int id = blockIdx.x;
  const int p = (id >> 3) & 15;             // q-pair index [0,16)
  const int bh = (id & 7) * 8 + (id >> 7);  // head-batch, XCD-grouped
  const int q0t = p, q1t = 31 - p;
  const bf16* Qb = Q + (long)bh * 131072;
  const bf16* Kb = Kg + (long)bh * 131072;
  const bf16* Vb = VT + (long)bh * 131072;
  bf16* Pw = &Ps[wid][0];
  const int qloc = wid * 16 + l15;

  bf16x8 ones;
#pragma unroll
  for (int j = 0; j < 8; ++j) ones[j] = (bf16)1.0f;

  bf16x8 qf0[2], qf1[2];
#pragma unroll
  for (int kk = 0; kk < 2; ++kk) {
    qf0[kk] = *(const bf16x8*)(Qb + (long)(q0t * 64 + qloc) * 64 + kk * 32 +
                               quad * 8);
    qf1[kk] = *(const bf16x8*)(Qb + (long)(q1t * 64 + qloc) * 64 + kk * 32 +
                               quad * 8);
  }
  f32x4 acc0[4] = {}, acc1[4] = {};
  f32x4 accL0 = {}, accL1 = {};

  for (int kt = 0; kt <= q1t; ++kt) {
#pragma unroll
    for (int it = 0; it < 2; ++it) {
      int chunk = it * 256 + tid;
      int r = chunk >> 3;
      int c = (((chunk & 7) ^ (r & 7)) << 3);
      int ldsbase = (it * 256 + wid * 64) * 16;
      async16(Kb + (long)(kt * 64 + r) * 64 + c, (char*)Ks + ldsbase);
      async16(Vb + (long)r * 2048 + kt * 64 + c, (char*)Vs + ldsbase);
    }
    __syncthreads();
    attn_step(Ks, Vs, Pw, qf1, ones, acc1, accL1, quad, l15, qloc, kt == q1t);
    if (kt <= q0t)
      attn_step(Ks, Vs, Pw, qf0, ones, acc0, accL0, quad, l15, qloc,
                kt == q0t);
    __syncthreads();
  }

  // epilogue: accL rows already aligned with accO rows -> no shuffles
  const int b = bh >> 4, h = bh & 15;
#pragma unroll
  for (int r = 0; r < 4; ++r) {
    float lr0 = 1.0f / accL0[r];
    float lr1 = 1.0f / accL1[r];
#pragma unroll
    for (int nt = 0; nt < 4; ++nt) {
      int d = h * 64 + nt * 16 + l15;
      int qg0 = q0t * 64 + wid * 16 + quad * 4 + r;
      int qg1 = q1t * 64 + wid * 16 + quad * 4 + r;
      Out[(long)(b * 2048 + qg0) * 1024 + d] = (bf16)(acc0[nt][r] * lr0);
      Out[(long)(b * 2048 + qg1) * 1024 + d] = (bf16)(acc1[nt][r] * lr1);
    }
  }
}

// ---------------------------------------------------------------------------
// Workspace layout (bytes):
//   xb  @ 0         (16,777,216)  -- reused as attn output
//   wqb @ 16777216  (2 MiB) \  [w_q; w_k] contiguous for fused QK GEMM,
//   wkb @ 18874368  (2 MiB) |  [w_v; w_o] follow for fused cast
//   wvb @ 20971520  (2 MiB) |
//   wob @ 23068672  (2 MiB) /
//   Qb  @ 25165824  (16,777,216)  (b,h,s,d) bf16, pre-scaled by QSCALE
//   Kb  @ 41943040  (16,777,216)  (b,h,s,d) bf16
//   VTb @ 58720256  (16,777,216)  (b,h,d,s) bf16
//   csT @ 75497472  (   524,288)  fused cos/sin float2 table
// ---------------------------------------------------------------------------
extern "C" void kernel_launch(void* const* d_in, const int* in_sizes, int n_in,
                              void* d_out, int out_size, void* d_ws,
                              size_t ws_size, hipStream_t stream) {
  const float* x = (const float*)d_in[0];
  const float* w_q = (const float*)d_in[1];
  const float* w_k = (const float*)d_in[2];
  const float* w_v = (const float*)d_in[3];
  const float* w_o = (const float*)d_in[4];
  const float* cosT = (const float*)d_in[5];
  const float* sinT = (const float*)d_in[6];

  char* ws = (char*)d_ws;
  bf16* xb = (bf16*)(ws + 0);
  bf16* wqb = (bf16*)(ws + 16777216);
  bf16* wvb = (bf16*)(ws + 20971520);
  bf16* wob = (bf16*)(ws + 23068672);
  bf16* Qb = (bf16*)(ws + 25165824);
  bf16* Kb = (bf16*)(ws + 41943040);
  bf16* VTb = (bf16*)(ws + 58720256);
  float2* csT = (float2*)(ws + 75497472);
  bf16* attnb = xb;

  // fused cast: x + all 4 weights + cos/sin float2 fusion in one launch
  cast_all_kernel<<<12544, 256, 0, stream>>>(x, w_q, w_k, w_v, w_o, cosT,
                                             sinT, xb, wqb, csT);

  // merged Q/K (+RoPE, Schraudolph pre-scale) and V^T projections.
  // BK=64 single-buffer; 1024 QK + 512 V blocks (128x128), XCD chunks.
  gemm_qkv<<<1536, 256, 0, stream>>>(xb, wqb, wvb, Qb, VTb, csT);

  // balanced causal flash attention -> (b,s,e) bf16 (R13-exact)
  attn_kernel<<<1024, 256, 0, stream>>>(Qb, Kb, VTb, attnb);

  // output projection -> fp32 (128x128 tiles, 512 blocks, XCD chunks)
  gemm_out<<<512, 256, 0, stream>>>(attnb, wob, (float*)d_out);
}